// Round 4
// baseline (19389.792 us; speedup 1.0000x reference)
//
#include <hip/hip_runtime.h>
#include <hip/hip_bf16.h>
#include <hip/hip_cooperative_groups.h>
#include <math.h>

namespace cg = cooperative_groups;

#define B_ 128
#define T_ 256
#define F_ 64
#define H_ 512
#define G4_ 2048

// dynamic LDS layout (bytes)
#define WH_OFF 0        // 4 waves x 16KB Wh fragments
#define WX_OFF 65536    // 4 waves x 16KB Wx fragments
#define G_OFF  131072   // float g[4][32][17] = 8704B
#define SMEM_TOTAL 139776

typedef __attribute__((ext_vector_type(8))) short bf16x8;
typedef __attribute__((ext_vector_type(4))) float f32x4;

__device__ __forceinline__ float sigmoidf_(float x) { return 1.f / (1.f + expf(-x)); }

// ---- transpose+cast four [512,2048] fp32 weight mats -> [2048,512] bf16 ----
__global__ __launch_bounds__(256) void transpose_cast_k(
    const float* __restrict__ s0, const float* __restrict__ s1,
    const float* __restrict__ s2, const float* __restrict__ s3,
    __hip_bfloat16* __restrict__ dst)
{
  __shared__ float lds[64][65];
  const float* src = (blockIdx.z == 0) ? s0 : (blockIdx.z == 1) ? s1 : (blockIdx.z == 2) ? s2 : s3;
  __hip_bfloat16* d = dst + (size_t)blockIdx.z * (G4_ * H_);
  int n0 = blockIdx.x * 64, k0 = blockIdx.y * 64;
  int tx = threadIdx.x & 63, ty = threadIdx.x >> 6;
#pragma unroll
  for (int r = 0; r < 16; r++) { int k = r * 4 + ty; lds[k][tx] = src[(size_t)(k0 + k) * G4_ + n0 + tx]; }
  __syncthreads();
#pragma unroll
  for (int r = 0; r < 16; r++) { int n = r * 4 + ty; d[(size_t)(n0 + n) * H_ + k0 + tx] = __float2bfloat16(lds[tx][n]); }
}

// ---- cast W1 to bf16 + zero state buffers ----
__global__ void prep_misc_k(const float* __restrict__ w1, __hip_bfloat16* __restrict__ w1b,
                            float* __restrict__ zbase, int nzero)
{
  int i = blockIdx.x * blockDim.x + threadIdx.x;
  int stride = gridDim.x * blockDim.x;
  for (int k = i; k < F_ * H_; k += stride) w1b[k] = __float2bfloat16(w1[k]);
  for (int k = i; k < nzero; k += stride) zbase[k] = 0.f;
}

// ---- dense1 + spectral-norm row normalization; h0 out as bf16 [B*T, H] ----
__global__ __launch_bounds__(512) void dense1_k(
    const float* __restrict__ x, const __hip_bfloat16* __restrict__ w1b,
    const float* __restrict__ b1, __hip_bfloat16* __restrict__ h0)
{
  __shared__ float red[8];
  int j = threadIdx.x;
  int wave = j >> 6, lane = j & 63;
  float wcol[64];
#pragma unroll
  for (int k = 0; k < 64; k++) wcol[k] = __bfloat162float(w1b[k * H_ + j]);
  float bj = b1[j];
  for (int r = 0; r < 32; r++) {
    int row = blockIdx.x * 32 + r;
    const float* xr = x + (size_t)row * F_;
    float acc = bj;
#pragma unroll
    for (int k = 0; k < 64; k++) acc += xr[k] * wcol[k];
    float ss = acc * acc;
#pragma unroll
    for (int o = 32; o; o >>= 1) ss += __shfl_down(ss, o);
    if (lane == 0) red[wave] = ss;
    __syncthreads();
    float tot = red[0] + red[1] + red[2] + red[3] + red[4] + red[5] + red[6] + red[7];
    float sc = sqrtf(512.f) / fmaxf(sqrtf(tot), 1e-12f);
    h0[(size_t)row * H_ + j] = __float2bfloat16(acc * sc);
    __syncthreads();
  }
}

// ---- fused persistent LSTM1+LSTM2, diagonally pipelined, weights in LDS ----
// 256 blocks (1/CU): grp0 = blocks 0..127 run LSTM1 step s; grp1 = 128..255
// run LSTM2 step s-1. Per grp: 4 batch-strips(32) x 32 unit-strips(16).
// Wave w = gate w over a 32(batch)x16(unit) tile, K=1024 (h@Wh + x@Wx).
// KEY (round 4): each wave's Wh/Wx slices (16KB each) are staged ONCE into
// LDS in MFMA-fragment order (lane-consecutive => conflict-free ds_read_b128).
// LDS is per-CU and immune to the per-step device-scope fence that
// invalidates L1/L2 (round-2 counters showed the full 8MB weight set
// re-fetched from HBM every step). VGPR pressure stays at round-2 levels
// (the round-3 256-VGPR persistent preload produced wrong results).
__global__ __launch_bounds__(256) void lstm_fused_k(
    const __hip_bfloat16* __restrict__ h0,     // [B*T, H] dense1 output (LSTM1 x)
    __hip_bfloat16* __restrict__ seq,          // [B*T, H] LSTM1 output / LSTM2 x
    const __hip_bfloat16* __restrict__ wh1, const __hip_bfloat16* __restrict__ wx1,
    const float* __restrict__ bl1,
    const __hip_bfloat16* __restrict__ wh2, const __hip_bfloat16* __restrict__ wx2,
    const float* __restrict__ bl2,
    __hip_bfloat16* __restrict__ h1A, __hip_bfloat16* __restrict__ h1B,
    __hip_bfloat16* __restrict__ h2A, __hip_bfloat16* __restrict__ h2B,
    float* __restrict__ h2f)                   // [B, H] fp32 final h of LSTM2
{
  extern __shared__ char smem[];
  cg::grid_group grid = cg::this_grid();
  const int tid = threadIdx.x;
  const int wave = tid >> 6;
  const int lane = tid & 63;
  const int lr = lane & 15;   // m (A-rows) / n (B-cols) within 16-tile
  const int lk = lane >> 4;   // k-octet quad
  const int bid = blockIdx.x;
  const int grp = bid >> 7;
  const int lid = bid & 127;
  const int bb = lid & 3;     // batch strip (32 rows)
  const int bu = lid >> 2;    // unit strip (16 cols), 0..31
  const int m0 = bb * 32;
  const int u0 = bu * 16;
  const int gcol = wave * H_ + u0 + lr;  // this lane's gate-column in [0,2048)

  const __hip_bfloat16* Wht = grp ? wh2 : wh1;
  const __hip_bfloat16* Wxt = grp ? wx2 : wx1;
  const float* bias = grp ? bl2 : bl1;
  const __hip_bfloat16* xsrc = grp ? (const __hip_bfloat16*)seq : h0;
  __hip_bfloat16* hb0 = grp ? h2A : h1A;
  __hip_bfloat16* hb1 = grp ? h2B : h1B;

  char* whs = smem + WH_OFF + wave * 16384;
  char* wxs = smem + WX_OFF + wave * 16384;
  float* gld = (float*)(smem + G_OFF);   // g[gate][m][u] as [4][32][17]

  const float bias0 = bias[gcol];
  float creg[2] = {0.f, 0.f};

  // ---- stage this wave's weight slices into LDS, fragment order (once) ----
  {
    const __hip_bfloat16* hsrcw = Wht + (size_t)gcol * H_ + lk * 8;
    const __hip_bfloat16* xsrcw = Wxt + (size_t)gcol * H_ + lk * 8;
#pragma unroll
    for (int i = 0; i < 16; i++) {
      *(bf16x8*)(whs + i * 1024 + lane * 16) = *(const bf16x8*)(hsrcw + i * 32);
      *(bf16x8*)(wxs + i * 1024 + lane * 16) = *(const bf16x8*)(xsrcw + i * 32);
    }
  }
  __syncthreads();

  for (int s = 0; s <= T_; s++) {
    const int t = grp ? (s - 1) : s;
    const bool active = grp ? (s >= 1) : (s < T_);
    if (active) {
      const __hip_bfloat16* hin = (t & 1) ? hb1 : hb0;
      __hip_bfloat16* hout = (t & 1) ? hb0 : hb1;

      f32x4 acc0 = {0.f, 0.f, 0.f, 0.f};   // batch rows m0..m0+15
      f32x4 acc1 = {0.f, 0.f, 0.f, 0.f};   // batch rows m0+16..m0+31

      // K-loop 1: h_prev @ Wh (A from global, B from LDS)
      {
        const __hip_bfloat16* a0p = hin + (size_t)(m0 + lr) * H_ + lk * 8;
        const __hip_bfloat16* a1p = a0p + 16 * H_;
#pragma unroll
        for (int i = 0; i < 16; i++) {
          bf16x8 a0 = *(const bf16x8*)(a0p + i * 32);
          bf16x8 a1 = *(const bf16x8*)(a1p + i * 32);
          bf16x8 bw = *(bf16x8*)(whs + i * 1024 + lane * 16);
          acc0 = __builtin_amdgcn_mfma_f32_16x16x32_bf16(a0, bw, acc0, 0, 0, 0);
          acc1 = __builtin_amdgcn_mfma_f32_16x16x32_bf16(a1, bw, acc1, 0, 0, 0);
        }
      }
      // K-loop 2: x_t @ Wx (x rows at (b*T + t))
      {
        const __hip_bfloat16* a0p = xsrc + ((size_t)(m0 + lr) * T_ + t) * H_ + lk * 8;
        const __hip_bfloat16* a1p = xsrc + ((size_t)(m0 + 16 + lr) * T_ + t) * H_ + lk * 8;
#pragma unroll
        for (int i = 0; i < 16; i++) {
          bf16x8 a0 = *(const bf16x8*)(a0p + i * 32);
          bf16x8 a1 = *(const bf16x8*)(a1p + i * 32);
          bf16x8 bw = *(bf16x8*)(wxs + i * 1024 + lane * 16);
          acc0 = __builtin_amdgcn_mfma_f32_16x16x32_bf16(a0, bw, acc0, 0, 0, 0);
          acc1 = __builtin_amdgcn_mfma_f32_16x16x32_bf16(a1, bw, acc1, 0, 0, 0);
        }
      }

      // stage pre-activation gates in LDS: g[gate][m][u]
#pragma unroll
      for (int r = 0; r < 4; r++) {
        // C/D layout: col = lane&15, row = (lane>>4)*4 + r
        gld[wave * 544 + (lk * 4 + r) * 17 + lr]        = acc0[r] + bias0;
        gld[wave * 544 + (16 + lk * 4 + r) * 17 + lr]   = acc1[r] + bias0;
      }
      __syncthreads();

#pragma unroll
      for (int j = 0; j < 2; j++) {
        int e = tid + 256 * j;
        int m = e >> 4, u = e & 15;
        float iv = sigmoidf_(gld[0 * 544 + m * 17 + u]);
        float fv = sigmoidf_(gld[1 * 544 + m * 17 + u]);
        float cb = tanhf(gld[2 * 544 + m * 17 + u]);
        float ov = sigmoidf_(gld[3 * 544 + m * 17 + u]);
        float cn = fv * creg[j] + iv * cb;
        creg[j] = cn;
        float hv = ov * tanhf(cn);
        __hip_bfloat16 hb = __float2bfloat16(hv);
        int gi = (m0 + m) * H_ + u0 + u;
        hout[gi] = hb;
        if (grp == 0) {
          seq[((size_t)(m0 + m) * T_ + t) * H_ + u0 + u] = hb;
        } else if (t == T_ - 1) {
          h2f[gi] = hv;
        }
      }
    }
    __threadfence();   // release: h/seq writes visible device-wide
    grid.sync();       // also the intra-block barrier protecting gld[] reuse
    __threadfence();   // acquire: invalidate stale L1/L2 before re-reading h
  }
}

// ---- LayerNorm + dense2(relu) + dense3; one block per batch row ----
__global__ __launch_bounds__(256) void final_k(
    const float* __restrict__ h2, const float* __restrict__ gamma, const float* __restrict__ beta,
    const float* __restrict__ W2, const float* __restrict__ b2,
    const float* __restrict__ W3, const float* __restrict__ b3, float* __restrict__ out)
{
  __shared__ float y[512];
  __shared__ float redS[4], redQ[4], redP[4];
  int b = blockIdx.x, tid = threadIdx.x;
  int wave = tid >> 6, lane = tid & 63;
  float v0 = h2[b * H_ + tid], v1 = h2[b * H_ + 256 + tid];
  float s = v0 + v1, q = v0 * v0 + v1 * v1;
#pragma unroll
  for (int o = 32; o; o >>= 1) { s += __shfl_down(s, o); q += __shfl_down(q, o); }
  if (lane == 0) { redS[wave] = s; redQ[wave] = q; }
  __syncthreads();
  float tot = redS[0] + redS[1] + redS[2] + redS[3];
  float totq = redQ[0] + redQ[1] + redQ[2] + redQ[3];
  float mu = tot * (1.f / 512.f);
  float var = totq * (1.f / 512.f) - mu * mu;
  float rs = rsqrtf(var + 1e-3f);
  y[tid]       = (v0 - mu) * rs * gamma[tid] + beta[tid];
  y[tid + 256] = (v1 - mu) * rs * gamma[tid + 256] + beta[tid + 256];
  __syncthreads();
  float acc = b2[tid];
  for (int k = 0; k < 512; k++) acc += y[k] * W2[k * 256 + tid];
  float pv = fmaxf(acc, 0.f) * W3[tid];
#pragma unroll
  for (int o = 32; o; o >>= 1) pv += __shfl_down(pv, o);
  if (lane == 0) redP[wave] = pv;
  __syncthreads();
  if (tid == 0) out[b] = redP[0] + redP[1] + redP[2] + redP[3] + b3[0];
}

extern "C" void kernel_launch(void* const* d_in, const int* in_sizes, int n_in,
                              void* d_out, int out_size, void* d_ws, size_t ws_size,
                              hipStream_t stream)
{
  (void)in_sizes; (void)n_in; (void)out_size; (void)ws_size;
  const float* x    = (const float*)d_in[0];
  const float* W1   = (const float*)d_in[1];
  const float* b1   = (const float*)d_in[2];
  const float* Wx1  = (const float*)d_in[3];
  const float* Wh1  = (const float*)d_in[4];
  const float* bl1  = (const float*)d_in[5];
  const float* Wx2  = (const float*)d_in[6];
  const float* Wh2  = (const float*)d_in[7];
  const float* bl2  = (const float*)d_in[8];
  const float* gam  = (const float*)d_in[9];
  const float* bet  = (const float*)d_in[10];
  const float* W2   = (const float*)d_in[11];
  const float* b2   = (const float*)d_in[12];
  const float* W3   = (const float*)d_in[13];
  const float* b3   = (const float*)d_in[14];

  char* p = (char*)d_ws;
  const size_t MB = 1024 * 1024;
  __hip_bfloat16* wx1t = (__hip_bfloat16*)(p + 0 * MB);
  __hip_bfloat16* wh1t = (__hip_bfloat16*)(p + 2 * MB);
  __hip_bfloat16* wx2t = (__hip_bfloat16*)(p + 4 * MB);
  __hip_bfloat16* wh2t = (__hip_bfloat16*)(p + 6 * MB);
  __hip_bfloat16* w1b  = (__hip_bfloat16*)(p + 8 * MB);
  __hip_bfloat16* h0   = (__hip_bfloat16*)(p + 9 * MB);   // 32 MB
  __hip_bfloat16* seq  = (__hip_bfloat16*)(p + 41 * MB);  // 32 MB
  char* st = p + 73 * MB;
  __hip_bfloat16* h1A = (__hip_bfloat16*)st;
  __hip_bfloat16* h1B = h1A + B_ * H_;
  __hip_bfloat16* h2A = h1B + B_ * H_;
  __hip_bfloat16* h2B = h2A + B_ * H_;
  float* h2f = (float*)(st + 512 * 1024);
  int nzero = (int)((512 * 1024 + 256 * 1024) / 4);  // h bufs + h2f

  transpose_cast_k<<<dim3(32, 8, 4), 256, 0, stream>>>(Wx1, Wh1, Wx2, Wh2, wx1t);
  prep_misc_k<<<256, 256, 0, stream>>>(W1, w1b, (float*)st, nzero);
  dense1_k<<<1024, 512, 0, stream>>>(x, w1b, b1, h0);

  void* args[] = { (void*)&h0, (void*)&seq,
                   (void*)&wh1t, (void*)&wx1t, (void*)&bl1,
                   (void*)&wh2t, (void*)&wx2t, (void*)&bl2,
                   (void*)&h1A, (void*)&h1B, (void*)&h2A, (void*)&h2B,
                   (void*)&h2f };
  hipLaunchCooperativeKernel((void*)lstm_fused_k, dim3(256), dim3(256), args,
                             SMEM_TOTAL, stream);

  final_k<<<128, 256, 0, stream>>>(h2f, gam, bet, W2, b2, W3, b3, (float*)d_out);
}

// Round 5
// 4569.239 us; speedup vs baseline: 4.2435x; 4.2435x over previous
//
#include <hip/hip_runtime.h>
#include <hip/hip_bf16.h>
#include <math.h>

#define B_ 128
#define T_ 256
#define F_ 64
#define H_ 512
#define G4_ 2048

// dynamic LDS layout (bytes)
#define WH_OFF 0        // 4 waves x 16KB Wh fragments
#define WX_OFF 65536    // 4 waves x 16KB Wx fragments
#define G_OFF  131072   // float g[4][32][17] = 8704B
#define SMEM_TOTAL 139776

typedef __attribute__((ext_vector_type(8))) short bf16x8;
typedef __attribute__((ext_vector_type(4))) float f32x4;

__device__ __forceinline__ float sigmoidf_(float x) { return 1.f / (1.f + expf(-x)); }

// agent-scope (device-coherent) 16B fragment load: bypasses per-XCD stale caches
__device__ __forceinline__ bf16x8 coh_frag(const __hip_bfloat16* p) {
  union { unsigned long long q[2]; bf16x8 v; } u;
  u.q[0] = __hip_atomic_load((const unsigned long long*)p,       __ATOMIC_RELAXED, __HIP_MEMORY_SCOPE_AGENT);
  u.q[1] = __hip_atomic_load(((const unsigned long long*)p) + 1, __ATOMIC_RELAXED, __HIP_MEMORY_SCOPE_AGENT);
  return u.v;
}

__device__ __forceinline__ void coh_store_u32(unsigned* p, unsigned v) {
  __hip_atomic_store(p, v, __ATOMIC_RELAXED, __HIP_MEMORY_SCOPE_AGENT);
}
__device__ __forceinline__ unsigned coh_load_u32(const unsigned* p) {
  return __hip_atomic_load(p, __ATOMIC_RELAXED, __HIP_MEMORY_SCOPE_AGENT);
}

// Contention-free grid barrier: per-block arrival flags (no RMW), leader polls,
// go-counter release. Monotonic step ids; flags zeroed by prep each launch.
// Every thread drains its own vmem queue first, so all agent-scope data stores
// are at the coherence point before the arrival flag is published.
__device__ __forceinline__ void flag_barrier(unsigned* arrive, unsigned* go,
                                             int bid, int tid, unsigned s1) {
  asm volatile("s_waitcnt vmcnt(0)" ::: "memory");  // per-wave drain (all waves)
  __syncthreads();                                  // whole block drained
  if (bid == 0) {
    if (tid > 0) {  // thread t waits for block t's arrival
      while (coh_load_u32(&arrive[tid]) < s1) __builtin_amdgcn_s_sleep(1);
    }
    __syncthreads();
    if (tid == 0) coh_store_u32(go, s1);
  } else {
    if (tid == 0) {
      coh_store_u32(&arrive[bid], s1);
      while (coh_load_u32(go) < s1) __builtin_amdgcn_s_sleep(1);
    }
    __syncthreads();
  }
  asm volatile("" ::: "memory");  // no hoisting of data loads above the barrier
}

// ---- transpose+cast four [512,2048] fp32 weight mats -> [2048,512] bf16 ----
__global__ __launch_bounds__(256) void transpose_cast_k(
    const float* __restrict__ s0, const float* __restrict__ s1,
    const float* __restrict__ s2, const float* __restrict__ s3,
    __hip_bfloat16* __restrict__ dst)
{
  __shared__ float lds[64][65];
  const float* src = (blockIdx.z == 0) ? s0 : (blockIdx.z == 1) ? s1 : (blockIdx.z == 2) ? s2 : s3;
  __hip_bfloat16* d = dst + (size_t)blockIdx.z * (G4_ * H_);
  int n0 = blockIdx.x * 64, k0 = blockIdx.y * 64;
  int tx = threadIdx.x & 63, ty = threadIdx.x >> 6;
#pragma unroll
  for (int r = 0; r < 16; r++) { int k = r * 4 + ty; lds[k][tx] = src[(size_t)(k0 + k) * G4_ + n0 + tx]; }
  __syncthreads();
#pragma unroll
  for (int r = 0; r < 16; r++) { int n = r * 4 + ty; d[(size_t)(n0 + n) * H_ + k0 + tx] = __float2bfloat16(lds[tx][n]); }
}

// ---- cast W1 to bf16 + zero state buffers & barrier flags ----
__global__ void prep_misc_k(const float* __restrict__ w1, __hip_bfloat16* __restrict__ w1b,
                            float* __restrict__ zbase, int nzero)
{
  int i = blockIdx.x * blockDim.x + threadIdx.x;
  int stride = gridDim.x * blockDim.x;
  for (int k = i; k < F_ * H_; k += stride) w1b[k] = __float2bfloat16(w1[k]);
  for (int k = i; k < nzero; k += stride) zbase[k] = 0.f;
}

// ---- dense1 + spectral-norm row normalization; h0 out as bf16 [B*T, H] ----
__global__ __launch_bounds__(512) void dense1_k(
    const float* __restrict__ x, const __hip_bfloat16* __restrict__ w1b,
    const float* __restrict__ b1, __hip_bfloat16* __restrict__ h0)
{
  __shared__ float red[8];
  int j = threadIdx.x;
  int wave = j >> 6, lane = j & 63;
  float wcol[64];
#pragma unroll
  for (int k = 0; k < 64; k++) wcol[k] = __bfloat162float(w1b[k * H_ + j]);
  float bj = b1[j];
  for (int r = 0; r < 32; r++) {
    int row = blockIdx.x * 32 + r;
    const float* xr = x + (size_t)row * F_;
    float acc = bj;
#pragma unroll
    for (int k = 0; k < 64; k++) acc += xr[k] * wcol[k];
    float ss = acc * acc;
#pragma unroll
    for (int o = 32; o; o >>= 1) ss += __shfl_down(ss, o);
    if (lane == 0) red[wave] = ss;
    __syncthreads();
    float tot = red[0] + red[1] + red[2] + red[3] + red[4] + red[5] + red[6] + red[7];
    float sc = sqrtf(512.f) / fmaxf(sqrtf(tot), 1e-12f);
    h0[(size_t)row * H_ + j] = __float2bfloat16(acc * sc);
    __syncthreads();
  }
}

// ---- fused persistent LSTM1+LSTM2, diagonally pipelined, weights in LDS ----
// 256 blocks (1/CU): grp0 = blocks 0..127 run LSTM1 step s; grp1 = 128..255
// run LSTM2 step s-1. Per grp: 4 batch-strips(32) x 32 unit-strips(16).
// Wave w = gate w over a 32(batch)x16(unit) tile, K=1024 (h@Wh + x@Wx).
// Round 5: no grid.sync / __threadfence (round-4 counters: 75us/step of sync
// cost, machine 99% idle). Custom flag barrier (no RMW contention) + agent-
// scope atomic loads/stores for all cross-block data (h, seq). L2 is never
// invalidated, so LDS-staged weights AND plain-cached h0 stay warm.
__global__ __launch_bounds__(256) void lstm_fused_k(
    const __hip_bfloat16* __restrict__ h0,     // [B*T, H] dense1 output (LSTM1 x)
    __hip_bfloat16* __restrict__ seq,          // [B*T, H] LSTM1 out / LSTM2 x
    const __hip_bfloat16* __restrict__ wh1, const __hip_bfloat16* __restrict__ wx1,
    const float* __restrict__ bl1,
    const __hip_bfloat16* __restrict__ wh2, const __hip_bfloat16* __restrict__ wx2,
    const float* __restrict__ bl2,
    __hip_bfloat16* __restrict__ h1A, __hip_bfloat16* __restrict__ h1B,
    __hip_bfloat16* __restrict__ h2A, __hip_bfloat16* __restrict__ h2B,
    float* __restrict__ h2f,                   // [B, H] fp32 final h of LSTM2
    unsigned* flags)                           // arrive[0..255], go at [384]
{
  extern __shared__ char smem[];
  const int tid = threadIdx.x;
  const int wave = tid >> 6;
  const int lane = tid & 63;
  const int lr = lane & 15;   // m (A-rows) / n (B-cols) within 16-tile
  const int lk = lane >> 4;   // k-octet quad
  const int bid = blockIdx.x;
  const int grp = bid >> 7;
  const int lid = bid & 127;
  const int bb = lid & 3;     // batch strip (32 rows)
  const int bu = lid >> 2;    // unit strip (16 cols), 0..31
  const int m0 = bb * 32;
  const int u0 = bu * 16;
  const int gcol = wave * H_ + u0 + lr;  // this lane's gate-column in [0,2048)

  const __hip_bfloat16* Wht = grp ? wh2 : wh1;
  const __hip_bfloat16* Wxt = grp ? wx2 : wx1;
  const float* bias = grp ? bl2 : bl1;
  __hip_bfloat16* hb0 = grp ? h2A : h1A;
  __hip_bfloat16* hb1 = grp ? h2B : h1B;
  unsigned* arrive = flags;
  unsigned* go = flags + 384;

  char* whs = smem + WH_OFF + wave * 16384;
  char* wxs = smem + WX_OFF + wave * 16384;
  float* gld = (float*)(smem + G_OFF);   // g[gate][m][u] as [4][32][17]

  const float bias0 = bias[gcol];

  // epilogue mapping (static per thread): row m_e, unit pair 2*up_e, 2*up_e+1
  const int m_e = tid >> 3;
  const int up_e = tid & 7;
  float2 creg = {0.f, 0.f};

  // ---- stage this wave's weight slices into LDS, fragment order (once) ----
  {
    const __hip_bfloat16* hsrcw = Wht + (size_t)gcol * H_ + lk * 8;
    const __hip_bfloat16* xsrcw = Wxt + (size_t)gcol * H_ + lk * 8;
#pragma unroll
    for (int i = 0; i < 16; i++) {
      *(bf16x8*)(whs + i * 1024 + lane * 16) = *(const bf16x8*)(hsrcw + i * 32);
      *(bf16x8*)(wxs + i * 1024 + lane * 16) = *(const bf16x8*)(xsrcw + i * 32);
    }
  }
  __syncthreads();

  for (int s = 0; s <= T_; s++) {
    const int t = grp ? (s - 1) : s;
    const bool active = grp ? (s >= 1) : (s < T_);
    if (active) {
      const __hip_bfloat16* hin = (t & 1) ? hb1 : hb0;
      __hip_bfloat16* hout = (t & 1) ? hb0 : hb1;

      f32x4 acc0 = {0.f, 0.f, 0.f, 0.f};   // batch rows m0..m0+15
      f32x4 acc1 = {0.f, 0.f, 0.f, 0.f};   // batch rows m0+16..m0+31

      // K-loop 1: h_prev @ Wh (A coherent from global, B from LDS)
      {
        const __hip_bfloat16* a0p = hin + (size_t)(m0 + lr) * H_ + lk * 8;
        const __hip_bfloat16* a1p = a0p + 16 * H_;
#pragma unroll
        for (int i = 0; i < 16; i++) {
          bf16x8 a0 = coh_frag(a0p + i * 32);
          bf16x8 a1 = coh_frag(a1p + i * 32);
          bf16x8 bw = *(bf16x8*)(whs + i * 1024 + lane * 16);
          acc0 = __builtin_amdgcn_mfma_f32_16x16x32_bf16(a0, bw, acc0, 0, 0, 0);
          acc1 = __builtin_amdgcn_mfma_f32_16x16x32_bf16(a1, bw, acc1, 0, 0, 0);
        }
      }
      // K-loop 2: x_t @ Wx. grp0: x = h0 (plain, stable), grp1: x = seq (coherent)
      if (grp == 0) {
        const __hip_bfloat16* a0p = h0 + ((size_t)(m0 + lr) * T_ + t) * H_ + lk * 8;
        const __hip_bfloat16* a1p = h0 + ((size_t)(m0 + 16 + lr) * T_ + t) * H_ + lk * 8;
#pragma unroll
        for (int i = 0; i < 16; i++) {
          bf16x8 a0 = *(const bf16x8*)(a0p + i * 32);
          bf16x8 a1 = *(const bf16x8*)(a1p + i * 32);
          bf16x8 bw = *(bf16x8*)(wxs + i * 1024 + lane * 16);
          acc0 = __builtin_amdgcn_mfma_f32_16x16x32_bf16(a0, bw, acc0, 0, 0, 0);
          acc1 = __builtin_amdgcn_mfma_f32_16x16x32_bf16(a1, bw, acc1, 0, 0, 0);
        }
      } else {
        const __hip_bfloat16* a0p = seq + ((size_t)(m0 + lr) * T_ + t) * H_ + lk * 8;
        const __hip_bfloat16* a1p = seq + ((size_t)(m0 + 16 + lr) * T_ + t) * H_ + lk * 8;
#pragma unroll
        for (int i = 0; i < 16; i++) {
          bf16x8 a0 = coh_frag(a0p + i * 32);
          bf16x8 a1 = coh_frag(a1p + i * 32);
          bf16x8 bw = *(bf16x8*)(wxs + i * 1024 + lane * 16);
          acc0 = __builtin_amdgcn_mfma_f32_16x16x32_bf16(a0, bw, acc0, 0, 0, 0);
          acc1 = __builtin_amdgcn_mfma_f32_16x16x32_bf16(a1, bw, acc1, 0, 0, 0);
        }
      }

      // stage pre-activation gates in LDS: g[gate][m][u]
#pragma unroll
      for (int r = 0; r < 4; r++) {
        // C/D layout: col = lane&15, row = (lane>>4)*4 + r
        gld[wave * 544 + (lk * 4 + r) * 17 + lr]      = acc0[r] + bias0;
        gld[wave * 544 + (16 + lk * 4 + r) * 17 + lr] = acc1[r] + bias0;
      }
      __syncthreads();

      // elementwise: thread handles (m_e, units 2*up_e, 2*up_e+1)
      {
        const int gbase0 = m_e * 17 + 2 * up_e;
        float i0 = sigmoidf_(gld[0 * 544 + gbase0]);
        float i1 = sigmoidf_(gld[0 * 544 + gbase0 + 1]);
        float f0 = sigmoidf_(gld[1 * 544 + gbase0]);
        float f1 = sigmoidf_(gld[1 * 544 + gbase0 + 1]);
        float cb0 = tanhf(gld[2 * 544 + gbase0]);
        float cb1 = tanhf(gld[2 * 544 + gbase0 + 1]);
        float o0 = sigmoidf_(gld[3 * 544 + gbase0]);
        float o1 = sigmoidf_(gld[3 * 544 + gbase0 + 1]);
        float cn0 = f0 * creg.x + i0 * cb0;
        float cn1 = f1 * creg.y + i1 * cb1;
        creg.x = cn0; creg.y = cn1;
        float hv0 = o0 * tanhf(cn0);
        float hv1 = o1 * tanhf(cn1);
        union { __hip_bfloat16 h[2]; unsigned u; } pk;
        pk.h[0] = __float2bfloat16(hv0);
        pk.h[1] = __float2bfloat16(hv1);
        const int row = m0 + m_e;
        const int col = u0 + 2 * up_e;
        coh_store_u32((unsigned*)hout + (row * H_ + col) / 2, pk.u);
        if (grp == 0) {
          coh_store_u32((unsigned*)seq + (((size_t)row * T_ + t) * H_ + col) / 2, pk.u);
        } else if (t == T_ - 1) {
          float2* dst = (float2*)(h2f + row * H_ + col);
          float2 hv = {hv0, hv1};
          *dst = hv;   // plain: kernel-end flush covers final_k
        }
      }
    }
    if (s < T_) flag_barrier(arrive, go, bid, tid, (unsigned)(s + 1));
  }
}

// ---- LayerNorm + dense2(relu) + dense3; one block per batch row ----
__global__ __launch_bounds__(256) void final_k(
    const float* __restrict__ h2, const float* __restrict__ gamma, const float* __restrict__ beta,
    const float* __restrict__ W2, const float* __restrict__ b2,
    const float* __restrict__ W3, const float* __restrict__ b3, float* __restrict__ out)
{
  __shared__ float y[512];
  __shared__ float redS[4], redQ[4], redP[4];
  int b = blockIdx.x, tid = threadIdx.x;
  int wave = tid >> 6, lane = tid & 63;
  float v0 = h2[b * H_ + tid], v1 = h2[b * H_ + 256 + tid];
  float s = v0 + v1, q = v0 * v0 + v1 * v1;
#pragma unroll
  for (int o = 32; o; o >>= 1) { s += __shfl_down(s, o); q += __shfl_down(q, o); }
  if (lane == 0) { redS[wave] = s; redQ[wave] = q; }
  __syncthreads();
  float tot = redS[0] + redS[1] + redS[2] + redS[3];
  float totq = redQ[0] + redQ[1] + redQ[2] + redQ[3];
  float mu = tot * (1.f / 512.f);
  float var = totq * (1.f / 512.f) - mu * mu;
  float rs = rsqrtf(var + 1e-3f);
  y[tid]       = (v0 - mu) * rs * gamma[tid] + beta[tid];
  y[tid + 256] = (v1 - mu) * rs * gamma[tid + 256] + beta[tid + 256];
  __syncthreads();
  float acc = b2[tid];
  for (int k = 0; k < 512; k++) acc += y[k] * W2[k * 256 + tid];
  float pv = fmaxf(acc, 0.f) * W3[tid];
#pragma unroll
  for (int o = 32; o; o >>= 1) pv += __shfl_down(pv, o);
  if (lane == 0) redP[wave] = pv;
  __syncthreads();
  if (tid == 0) out[b] = redP[0] + redP[1] + redP[2] + redP[3] + b3[0];
}

extern "C" void kernel_launch(void* const* d_in, const int* in_sizes, int n_in,
                              void* d_out, int out_size, void* d_ws, size_t ws_size,
                              hipStream_t stream)
{
  (void)in_sizes; (void)n_in; (void)out_size; (void)ws_size;
  const float* x    = (const float*)d_in[0];
  const float* W1   = (const float*)d_in[1];
  const float* b1   = (const float*)d_in[2];
  const float* Wx1  = (const float*)d_in[3];
  const float* Wh1  = (const float*)d_in[4];
  const float* bl1  = (const float*)d_in[5];
  const float* Wx2  = (const float*)d_in[6];
  const float* Wh2  = (const float*)d_in[7];
  const float* bl2  = (const float*)d_in[8];
  const float* gam  = (const float*)d_in[9];
  const float* bet  = (const float*)d_in[10];
  const float* W2   = (const float*)d_in[11];
  const float* b2   = (const float*)d_in[12];
  const float* W3   = (const float*)d_in[13];
  const float* b3   = (const float*)d_in[14];

  char* p = (char*)d_ws;
  const size_t MB = 1024 * 1024;
  __hip_bfloat16* wx1t = (__hip_bfloat16*)(p + 0 * MB);
  __hip_bfloat16* wh1t = (__hip_bfloat16*)(p + 2 * MB);
  __hip_bfloat16* wx2t = (__hip_bfloat16*)(p + 4 * MB);
  __hip_bfloat16* wh2t = (__hip_bfloat16*)(p + 6 * MB);
  __hip_bfloat16* w1b  = (__hip_bfloat16*)(p + 8 * MB);
  __hip_bfloat16* h0   = (__hip_bfloat16*)(p + 9 * MB);   // 32 MB
  __hip_bfloat16* seq  = (__hip_bfloat16*)(p + 41 * MB);  // 32 MB
  char* st = p + 73 * MB;
  __hip_bfloat16* h1A = (__hip_bfloat16*)st;                       // 4x128KB
  __hip_bfloat16* h1B = h1A + B_ * H_;
  __hip_bfloat16* h2A = h1B + B_ * H_;
  __hip_bfloat16* h2B = h2A + B_ * H_;
  float* h2f = (float*)(st + 512 * 1024);                          // 256KB
  unsigned* flags = (unsigned*)(st + 512 * 1024 + 256 * 1024);     // 4KB
  int nzero = (int)((512 * 1024 + 256 * 1024 + 4096) / 4);

  transpose_cast_k<<<dim3(32, 8, 4), 256, 0, stream>>>(Wx1, Wh1, Wx2, Wh2, wx1t);
  prep_misc_k<<<256, 256, 0, stream>>>(W1, w1b, (float*)st, nzero);
  dense1_k<<<1024, 512, 0, stream>>>(x, w1b, b1, h0);

  void* args[] = { (void*)&h0, (void*)&seq,
                   (void*)&wh1t, (void*)&wx1t, (void*)&bl1,
                   (void*)&wh2t, (void*)&wx2t, (void*)&bl2,
                   (void*)&h1A, (void*)&h1B, (void*)&h2A, (void*)&h2B,
                   (void*)&h2f, (void*)&flags };
  hipLaunchCooperativeKernel((void*)lstm_fused_k, dim3(256), dim3(256), args,
                             SMEM_TOTAL, stream);

  final_k<<<128, 256, 0, stream>>>(h2f, gam, bet, W2, b2, W3, b3, (float*)d_out);
}